// Round 4
// baseline (344.699 us; speedup 1.0000x reference)
//
#include <hip/hip_runtime.h>

typedef __attribute__((ext_vector_type(8))) short bf16x8;
typedef __attribute__((ext_vector_type(4))) short s16x4;
typedef __attribute__((ext_vector_type(16))) float f32x16;

#define LOG2E 1.4426950408889634f
#define MASKV2 (-1442695.0f)          // -1e6 * log2(e): exp2 domain

__device__ __forceinline__ unsigned cvt_pk_bf16(float lo, float hi_) {
  unsigned r;
  asm("v_cvt_pk_bf16_f32 %0, %1, %2" : "=v"(r) : "v"(lo), "v"(hi_));
  return r;
}

// mask_idx dtype ambiguity (uint8 bool vs int32): int32 0/1 arrays have zero
// bytes at offsets %4 != 0. flag=1 -> uint8, flag=0 -> int32.
__global__ void detect_mask_kernel(const unsigned char* __restrict__ m, int* flag) {
  __shared__ int s;
  if (threadIdx.x == 0) s = 0;
  __syncthreads();
  int acc = 0;
  for (int i = threadIdx.x; i < 65536; i += 256)
    if (i & 3) acc += m[i];
  atomicAdd(&s, acc);
  __syncthreads();
  if (threadIdx.x == 0) flag[0] = (s > 0) ? 1 : 0;
}

__device__ __forceinline__ unsigned pk4(unsigned u) {
  unsigned t = u & 0x01010101u;
  return (t | (t >> 7) | (t >> 14) | (t >> 21)) & 0xFu;
}

// Pack mask (uint8 0/1 or int32 0/1) into 1 bit per element, linear order.
__global__ __launch_bounds__(256)
void pack_mask(const unsigned char* __restrict__ m, const int* __restrict__ flag,
               unsigned* __restrict__ bits, int n_u32) {
  const bool is8 = (flag[0] != 0);
  const int stride = gridDim.x * blockDim.x;
  for (int i = blockIdx.x * blockDim.x + threadIdx.x; i < n_u32; i += stride) {
    unsigned out;
    if (is8) {
      const uint4* p = (const uint4*)m + (size_t)i * 2;
      uint4 a = p[0], b = p[1];
      out = pk4(a.x) | (pk4(a.y) << 4) | (pk4(a.z) << 8) | (pk4(a.w) << 12)
          | (pk4(b.x) << 16) | (pk4(b.y) << 20) | (pk4(b.z) << 24) | (pk4(b.w) << 28);
    } else {
      const int4* p = (const int4*)m + (size_t)i * 8;
      out = 0;
#pragma unroll
      for (int j = 0; j < 8; ++j) {
        int4 v = p[j];
        out |= (unsigned)(v.x != 0) << (4 * j)
             | (unsigned)(v.y != 0) << (4 * j + 1)
             | (unsigned)(v.z != 0) << (4 * j + 2)
             | (unsigned)(v.w != 0) << (4 * j + 3);
      }
    }
    bits[i] = out;
  }
}

// BITS=true: mask from packed bitmask. BITS=false: direct gather (fallback).
template <bool BITS>
__global__ __launch_bounds__(512, 2)
void attn_fwd(const float* __restrict__ Qp, const float* __restrict__ Kp,
              const float* __restrict__ Vp, const unsigned char* __restrict__ M8,
              const unsigned* __restrict__ Bits,
              float* __restrict__ Op, const int* __restrict__ flag)
{
  const int tid  = threadIdx.x;
  const int lane = tid & 63;
  const int wv   = tid >> 6;        // 0..7
  const int hi   = lane >> 5;       // 0/1
  const int l31  = lane & 31;
  const int n    = blockIdx.x;
  // XCD-aware decode: all 8 q-blocks of batch b land on XCD b&7.
  const int b    = (n & 7) + 8 * (n >> 6);
  const int qt   = (n >> 3) & 7;
  const int q    = qt * 256 + wv * 32 + l31;   // this lane's q-row

  __shared__ __align__(16) short Kl[2][64 * 128];   // K tiles, XOR-swizzled
  __shared__ __align__(16) short Vt[2][128 * 64];   // V^T tiles, XOR-swizzled

  // ---- Q B-frags (col=q=lane&31, k-dim=d=dc*16+hi*8+j), scale*log2e folded ----
  const float qscale = 0.08838834764831845f * LOG2E;
  bf16x8 qf[8];
  {
    const float* qrow = Qp + ((size_t)b * 2048 + q) * 128;
#pragma unroll
    for (int dc = 0; dc < 8; ++dc) {
      const int d0 = dc * 16 + hi * 8;
      float4 x = *(const float4*)(qrow + d0);
      float4 y = *(const float4*)(qrow + d0 + 4);
      union { bf16x8 v; unsigned u[4]; } uu;
      uu.u[0] = cvt_pk_bf16(x.x * qscale, x.y * qscale);
      uu.u[1] = cvt_pk_bf16(x.z * qscale, x.w * qscale);
      uu.u[2] = cvt_pk_bf16(y.x * qscale, y.y * qscale);
      uu.u[3] = cvt_pk_bf16(y.z * qscale, y.w * qscale);
      qf[dc] = uu.v;
    }
  }

  f32x16 oacc[4];
#pragma unroll
  for (int g = 0; g < 4; ++g)
#pragma unroll
    for (int r = 0; r < 16; ++r) oacc[g][r] = 0.f;

  float mrun = -1e30f, lrun = 0.f;
  const unsigned* brow = Bits + ((size_t)b * 2048 + q) * 64;   // 64 dwords/row
  const unsigned char* mrow8  = M8 + ((size_t)b * 2048 + q) * (size_t)2048;
  const int*           mrow32 = (const int*)M8 + ((size_t)b * 2048 + q) * (size_t)2048;
  const bool is8 = BITS ? true : (flag[0] != 0);

  const int xk = 8 * (l31 & 15);   // K-lds XOR key (shorts)
  const int xv = 8 * (l31 >> 2);   // V-lds XOR key (shorts)
  const int db = tid & 31, kb = tid >> 5;   // V staging: 32 x 16 blocks of 4x4
  const size_t kvrow0 = (size_t)b * 2048 * 128;
  const int krow0 = tid >> 5;              // K staging: +16 per chunk
  const int kcol0 = (tid & 31) * 4;

  // ---- prologue: stage tile 0 into buf 0 ----
  {
#pragma unroll
    for (int i = 0; i < 4; ++i) {
      const int row = krow0 + i * 16;
      float4 x = *(const float4*)(Kp + kvrow0 + row * 128 + kcol0);
      union { s16x4 v; unsigned u[2]; } pk;
      pk.u[0] = cvt_pk_bf16(x.x, x.y);
      pk.u[1] = cvt_pk_bf16(x.z, x.w);
      *(s16x4*)&Kl[0][row * 128 + (kcol0 ^ (8 * (row & 15)))] = pk.v;
    }
    union { float4 v; float f[4]; } r0, r1, r2, r3;
    r0.v = *(const float4*)(Vp + kvrow0 + (kb * 4 + 0) * 128 + db * 4);
    r1.v = *(const float4*)(Vp + kvrow0 + (kb * 4 + 1) * 128 + db * 4);
    r2.v = *(const float4*)(Vp + kvrow0 + (kb * 4 + 2) * 128 + db * 4);
    r3.v = *(const float4*)(Vp + kvrow0 + (kb * 4 + 3) * 128 + db * 4);
    const int cs = (kb * 4) ^ (8 * (db & 7));
#pragma unroll
    for (int j = 0; j < 4; ++j) {
      union { s16x4 v; unsigned u[2]; } pk;
      pk.u[0] = cvt_pk_bf16(r0.f[j], r1.f[j]);
      pk.u[1] = cvt_pk_bf16(r2.f[j], r3.f[j]);
      *(s16x4*)&Vt[0][(db * 4 + j) * 64 + cs] = pk.v;
    }
  }
  __syncthreads();

  for (int kt = 0; kt < 32; ++kt) {
    const int cur = kt & 1;
    const short* klb = &Kl[cur][0];
    const short* vtb = &Vt[cur][0];

    // ---- issue next K/V tile loads (consumed right after QK) ----
    const int ktn = (kt < 31) ? kt + 1 : 31;
    const size_t nb = kvrow0 + (size_t)ktn * 64 * 128;
    float4 kreg[4];
#pragma unroll
    for (int i = 0; i < 4; ++i)
      kreg[i] = *(const float4*)(Kp + nb + (krow0 + i * 16) * 128 + kcol0);
    float4 vreg[4];
#pragma unroll
    for (int i = 0; i < 4; ++i)
      vreg[i] = *(const float4*)(Vp + nb + (kb * 4 + i) * 128 + db * 4);

    // ---- issue this tile's mask ----
    uint2 mwb;
    unsigned mg[8];
    if (BITS) {
      mwb = *(const uint2*)(brow + kt * 2);
    } else if (is8) {
#pragma unroll
      for (int m = 0; m < 4; ++m) {
        mg[m]     = *(const unsigned*)(mrow8 + kt * 64 + hi * 4 + m * 8);
        mg[4 + m] = *(const unsigned*)(mrow8 + kt * 64 + 32 + hi * 4 + m * 8);
      }
    }

    // ---- S^T = K · Q^T (swapped): lane holds S[k][q=l31] ----
    f32x16 s0m, s1m;
#pragma unroll
    for (int r = 0; r < 16; ++r) { s0m[r] = 0.f; s1m[r] = 0.f; }
    __builtin_amdgcn_s_setprio(1);
#pragma unroll
    for (int dc = 0; dc < 8; ++dc) {
      const int colb = (dc * 16 + hi * 8) ^ xk;
      bf16x8 a0 = *(const bf16x8*)&klb[l31 * 128 + colb];
      bf16x8 a1 = *(const bf16x8*)&klb[(32 + l31) * 128 + colb];
      s0m = __builtin_amdgcn_mfma_f32_32x32x16_bf16(a0, qf[dc], s0m, 0, 0, 0);
      s1m = __builtin_amdgcn_mfma_f32_32x32x16_bf16(a1, qf[dc], s1m, 0, 0, 0);
    }
    __builtin_amdgcn_s_setprio(0);

    // ---- write staged K/V tile now (frees kreg/vreg before softmax/PV) ----
    {
      short* kln = &Kl[cur ^ 1][0];
      short* vtn = &Vt[cur ^ 1][0];
#pragma unroll
      for (int i = 0; i < 4; ++i) {
        const int row = krow0 + i * 16;
        union { s16x4 v; unsigned u[2]; } pk;
        pk.u[0] = cvt_pk_bf16(kreg[i].x, kreg[i].y);
        pk.u[1] = cvt_pk_bf16(kreg[i].z, kreg[i].w);
        *(s16x4*)&kln[row * 128 + (kcol0 ^ (8 * (row & 15)))] = pk.v;
      }
      const int cs = (kb * 4) ^ (8 * (db & 7));
#pragma unroll
      for (int j = 0; j < 4; ++j) {
        union { s16x4 v; unsigned u[2]; } pk;
        union { float4 v; float f[4]; } a0, a1, a2, a3;
        a0.v = vreg[0]; a1.v = vreg[1]; a2.v = vreg[2]; a3.v = vreg[3];
        pk.u[0] = cvt_pk_bf16(a0.f[j], a1.f[j]);
        pk.u[1] = cvt_pk_bf16(a2.f[j], a3.f[j]);
        *(s16x4*)&vtn[(db * 4 + j) * 64 + cs] = pk.v;
      }
    }

    // ---- mask: reg r <-> k = 32*kk + (r&3) + 8*(r>>2) + 4*hi ----
    float p0[16], p1[16];
    if (BITS) {
      const unsigned sh0 = mwb.x >> (hi * 4);
      const unsigned sh1 = mwb.y >> (hi * 4);
#pragma unroll
      for (int r = 0; r < 16; ++r) {
        const int kb_ = (r & 3) + 8 * (r >> 2);
        p0[r] = ((sh0 >> kb_) & 1u) ? MASKV2 : s0m[r];
        p1[r] = ((sh1 >> kb_) & 1u) ? MASKV2 : s1m[r];
      }
    } else if (is8) {
#pragma unroll
      for (int m = 0; m < 4; ++m)
#pragma unroll
        for (int e = 0; e < 4; ++e) {
          p0[4 * m + e] = ((mg[m]     >> (8 * e)) & 0xffu) ? MASKV2 : s0m[4 * m + e];
          p1[4 * m + e] = ((mg[4 + m] >> (8 * e)) & 0xffu) ? MASKV2 : s1m[4 * m + e];
        }
    } else {
#pragma unroll
      for (int m = 0; m < 4; ++m) {
        int4 w0 = *(const int4*)(mrow32 + kt * 64 + hi * 4 + m * 8);
        int4 w1 = *(const int4*)(mrow32 + kt * 64 + 32 + hi * 4 + m * 8);
        p0[4 * m + 0] = w0.x ? MASKV2 : s0m[4 * m + 0];
        p0[4 * m + 1] = w0.y ? MASKV2 : s0m[4 * m + 1];
        p0[4 * m + 2] = w0.z ? MASKV2 : s0m[4 * m + 2];
        p0[4 * m + 3] = w0.w ? MASKV2 : s0m[4 * m + 3];
        p1[4 * m + 0] = w1.x ? MASKV2 : s1m[4 * m + 0];
        p1[4 * m + 1] = w1.y ? MASKV2 : s1m[4 * m + 1];
        p1[4 * m + 2] = w1.z ? MASKV2 : s1m[4 * m + 2];
        p1[4 * m + 3] = w1.w ? MASKV2 : s1m[4 * m + 3];
      }
    }

    // ---- online softmax in exp2 domain ----
    float tm = p0[0];
#pragma unroll
    for (int r = 1; r < 16; ++r) tm = fmaxf(tm, p0[r]);
#pragma unroll
    for (int r = 0; r < 16; ++r) tm = fmaxf(tm, p1[r]);
    tm = fmaxf(tm, __shfl_xor(tm, 32));

    if (__any(tm > mrun + 8.0f)) {        // defer-max (T13)
      float mnew = fmaxf(mrun, tm);
      float corr = __builtin_amdgcn_exp2f(mrun - mnew);
      mrun = mnew;
      lrun *= corr;
#pragma unroll
      for (int g = 0; g < 4; ++g)
#pragma unroll
        for (int r = 0; r < 16; ++r) oacc[g][r] *= corr;
    }

    float psum = 0.f;
#pragma unroll
    for (int r = 0; r < 16; ++r) { p0[r] = __builtin_amdgcn_exp2f(p0[r] - mrun); psum += p0[r]; }
#pragma unroll
    for (int r = 0; r < 16; ++r) { p1[r] = __builtin_amdgcn_exp2f(p1[r] - mrun); psum += p1[r]; }
    psum += __shfl_xor(psum, 32);
    lrun += psum;

    // ---- P (S^T C-layout) -> P^T B-frags, in-register ----
    unsigned pk0[8], pk1[8];
#pragma unroll
    for (int i = 0; i < 8; ++i) {
      pk0[i] = cvt_pk_bf16(p0[2 * i], p0[2 * i + 1]);
      pk1[i] = cvt_pk_bf16(p1[2 * i], p1[2 * i + 1]);
    }
    bf16x8 pa[4];
#pragma unroll
    for (int ks = 0; ks < 4; ++ks) {
      const int base = 4 * (ks & 1);
      unsigned o0, o1, sd0, sd1;
      if (ks < 2) {
        o0  = hi ? pk0[base + 2] : pk0[base + 0];
        o1  = hi ? pk0[base + 3] : pk0[base + 1];
        sd0 = hi ? pk0[base + 0] : pk0[base + 2];
        sd1 = hi ? pk0[base + 1] : pk0[base + 3];
      } else {
        o0  = hi ? pk1[base + 2] : pk1[base + 0];
        o1  = hi ? pk1[base + 3] : pk1[base + 1];
        sd0 = hi ? pk1[base + 0] : pk1[base + 2];
        sd1 = hi ? pk1[base + 1] : pk1[base + 3];
      }
      unsigned rec0 = (unsigned)__shfl_xor((int)sd0, 32);
      unsigned rec1 = (unsigned)__shfl_xor((int)sd1, 32);
      union { bf16x8 v; unsigned u[4]; } uu;
      uu.u[0] = hi ? rec0 : o0;
      uu.u[1] = hi ? rec1 : o1;
      uu.u[2] = hi ? o0 : rec0;
      uu.u[3] = hi ? o1 : rec1;
      pa[ks] = uu.v;
    }

    // ---- O^T += V^T · P^T ----
    __builtin_amdgcn_s_setprio(1);
#pragma unroll
    for (int g = 0; g < 4; ++g) {
      const int drow = g * 32 + l31;
#pragma unroll
      for (int ks = 0; ks < 4; ++ks) {
        bf16x8 va = *(const bf16x8*)&vtb[drow * 64 + ((ks * 16 + hi * 8) ^ xv)];
        oacc[g] = __builtin_amdgcn_mfma_f32_32x32x16_bf16(va, pa[ks], oacc[g], 0, 0, 0);
      }
    }
    __builtin_amdgcn_s_setprio(0);

    __syncthreads();
  }

  // ---- epilogue: O[q][d] = oacc/l; d = 32g + 4hi + 8m + e ----
  const float inv = 1.0f / lrun;
  float* orow = Op + ((size_t)b * 2048 + q) * 128;
#pragma unroll
  for (int g = 0; g < 4; ++g) {
#pragma unroll
    for (int m = 0; m < 4; ++m) {
      float4 o;
      o.x = oacc[g][4 * m + 0] * inv;
      o.y = oacc[g][4 * m + 1] * inv;
      o.z = oacc[g][4 * m + 2] * inv;
      o.w = oacc[g][4 * m + 3] * inv;
      *(float4*)(orow + g * 32 + hi * 4 + m * 8) = o;
    }
  }
}

extern "C" void kernel_launch(void* const* d_in, const int* in_sizes, int n_in,
                              void* d_out, int out_size, void* d_ws, size_t ws_size,
                              hipStream_t stream) {
  const float* qp = (const float*)d_in[0];
  const float* kp = (const float*)d_in[1];
  const float* vp = (const float*)d_in[2];
  const unsigned char* mp = (const unsigned char*)d_in[3];
  float* op = (float*)d_out;
  int* flag = (int*)d_ws;

  detect_mask_kernel<<<1, 256, 0, stream>>>(mp, flag);

  const int n_u32 = 32 * 2048 * 2048 / 32;               // 4,194,304 dwords
  const size_t need = 256 + (size_t)n_u32 * 4;           // ~16.8 MB
  if (ws_size >= need) {
    unsigned* bits = (unsigned*)((char*)d_ws + 256);
    pack_mask<<<4096, 256, 0, stream>>>(mp, flag, bits, n_u32);
    attn_fwd<true><<<256, 512, 0, stream>>>(qp, kp, vp, mp, bits, op, flag);
  } else {
    attn_fwd<false><<<256, 512, 0, stream>>>(qp, kp, vp, mp, (const unsigned*)d_ws, op, flag);
  }
}

// Round 5
// 295.910 us; speedup vs baseline: 1.1649x; 1.1649x over previous
//
#include <hip/hip_runtime.h>

typedef __attribute__((ext_vector_type(8))) short bf16x8;
typedef __attribute__((ext_vector_type(4))) short s16x4;
typedef __attribute__((ext_vector_type(16))) float f32x16;

#define LOG2E 1.4426950408889634f
#define MASKV2 (-1442695.0f)          // -1e6 * log2(e): exp2 domain

__device__ __forceinline__ unsigned cvt_pk_bf16(float lo, float hi_) {
  unsigned r;
  asm("v_cvt_pk_bf16_f32 %0, %1, %2" : "=v"(r) : "v"(lo), "v"(hi_));
  return r;
}

// mask_idx dtype ambiguity (uint8 bool vs int32): int32 0/1 arrays have zero
// bytes at offsets %4 != 0. flag=1 -> uint8, flag=0 -> int32.
__global__ void detect_mask_kernel(const unsigned char* __restrict__ m, int* flag) {
  __shared__ int s;
  if (threadIdx.x == 0) s = 0;
  __syncthreads();
  int acc = 0;
  for (int i = threadIdx.x; i < 65536; i += 256)
    if (i & 3) acc += m[i];
  atomicAdd(&s, acc);
  __syncthreads();
  if (threadIdx.x == 0) flag[0] = (s > 0) ? 1 : 0;
}

// Build per-(b,kt) bf16 tile images: 16 KB swizzled K + 16 KB swizzled V^T,
// byte-identical to the attn kernel's LDS layout, so in-loop staging is a
// raw linear copy (no cvt, no transpose, no swizzle math in the hot loop).
__global__ __launch_bounds__(512)
void build_images(const float* __restrict__ Kp, const float* __restrict__ Vp,
                  char* __restrict__ img)
{
  const int tid  = threadIdx.x;
  const int tile = blockIdx.x;          // b*32 + kt
  const int b = tile >> 5, kt = tile & 31;
  __shared__ __align__(16) short Kl[64 * 128];
  __shared__ __align__(16) short Vt[128 * 64];
  const size_t kvbase = ((size_t)b * 2048 + (size_t)kt * 64) * 128;

  const int krow0 = tid >> 5, kcol0 = (tid & 31) * 4;
#pragma unroll
  for (int i = 0; i < 4; ++i) {
    const int row = krow0 + i * 16;
    float4 x = *(const float4*)(Kp + kvbase + row * 128 + kcol0);
    union { s16x4 v; unsigned u[2]; } pk;
    pk.u[0] = cvt_pk_bf16(x.x, x.y);
    pk.u[1] = cvt_pk_bf16(x.z, x.w);
    *(s16x4*)&Kl[row * 128 + (kcol0 ^ (8 * (row & 15)))] = pk.v;
  }
  {
    const int db = tid & 31, kb = tid >> 5;
    union { float4 v; float f[4]; } r0, r1, r2, r3;
    r0.v = *(const float4*)(Vp + kvbase + (kb * 4 + 0) * 128 + db * 4);
    r1.v = *(const float4*)(Vp + kvbase + (kb * 4 + 1) * 128 + db * 4);
    r2.v = *(const float4*)(Vp + kvbase + (kb * 4 + 2) * 128 + db * 4);
    r3.v = *(const float4*)(Vp + kvbase + (kb * 4 + 3) * 128 + db * 4);
    const int cs = (kb * 4) ^ (8 * (db & 7));
#pragma unroll
    for (int j = 0; j < 4; ++j) {
      union { s16x4 v; unsigned u[2]; } pk;
      pk.u[0] = cvt_pk_bf16(r0.f[j], r1.f[j]);
      pk.u[1] = cvt_pk_bf16(r2.f[j], r3.f[j]);
      *(s16x4*)&Vt[(db * 4 + j) * 64 + cs] = pk.v;
    }
  }
  __syncthreads();
  char* o = img + (size_t)tile * 32768;
  *(uint4*)(o +     0 + tid * 16) = *(const uint4*)((const char*)Kl +    0 + tid * 16);
  *(uint4*)(o +  8192 + tid * 16) = *(const uint4*)((const char*)Kl + 8192 + tid * 16);
  *(uint4*)(o + 16384 + tid * 16) = *(const uint4*)((const char*)Vt +    0 + tid * 16);
  *(uint4*)(o + 24576 + tid * 16) = *(const uint4*)((const char*)Vt + 8192 + tid * 16);
}

// PRE=true: stage from pre-built bf16 images (linear copy). PRE=false: stage
// from f32 K/V with in-loop convert (fallback if ws too small).
template <bool PRE>
__global__ __launch_bounds__(512, 2)
void attn_fwd(const float* __restrict__ Qp, const float* __restrict__ Kp,
              const float* __restrict__ Vp, const unsigned char* __restrict__ M8,
              const char* __restrict__ img,
              float* __restrict__ Op, const int* __restrict__ flag)
{
  const int tid  = threadIdx.x;
  const int lane = tid & 63;
  const int wv   = tid >> 6;        // 0..7
  const int hi   = lane >> 5;       // 0/1
  const int l31  = lane & 31;
  const int n    = blockIdx.x;
  // XCD-aware decode: all 8 q-blocks of batch b land on XCD b&7.
  const int b    = (n & 7) + 8 * (n >> 6);
  const int qt   = (n >> 3) & 7;
  const int q    = qt * 256 + wv * 32 + l31;   // this lane's q-row
  const bool is8 = (flag[0] != 0);

  __shared__ __align__(16) short Kl[2][64 * 128];   // K tiles, XOR-swizzled
  __shared__ __align__(16) short Vt[2][128 * 64];   // V^T tiles, XOR-swizzled

  // ---- Q B-frags (col=q=lane&31, k-dim=d=dc*16+hi*8+j), scale*log2e folded ----
  const float qscale = 0.08838834764831845f * LOG2E;
  bf16x8 qf[8];
  {
    const float* qrow = Qp + ((size_t)b * 2048 + q) * 128;
#pragma unroll
    for (int dc = 0; dc < 8; ++dc) {
      const int d0 = dc * 16 + hi * 8;
      float4 x = *(const float4*)(qrow + d0);
      float4 y = *(const float4*)(qrow + d0 + 4);
      union { bf16x8 v; unsigned u[4]; } uu;
      uu.u[0] = cvt_pk_bf16(x.x * qscale, x.y * qscale);
      uu.u[1] = cvt_pk_bf16(x.z * qscale, x.w * qscale);
      uu.u[2] = cvt_pk_bf16(y.x * qscale, y.y * qscale);
      uu.u[3] = cvt_pk_bf16(y.z * qscale, y.w * qscale);
      qf[dc] = uu.v;
    }
  }

  f32x16 oacc[4];
#pragma unroll
  for (int g = 0; g < 4; ++g)
#pragma unroll
    for (int r = 0; r < 16; ++r) oacc[g][r] = 0.f;

  float mrun = -1e30f, lrun = 0.f;
  const unsigned char* mrow8  = M8 + ((size_t)b * 2048 + q) * (size_t)2048;
  const int*           mrow32 = (const int*)M8 + ((size_t)b * 2048 + q) * (size_t)2048;

  const int xk = 8 * (l31 & 15);   // K-lds XOR key (shorts)
  const int xv = 8 * (l31 >> 2);   // V-lds XOR key (shorts)
  const int db = tid & 31, kb = tid >> 5;
  const size_t kvrow0 = (size_t)b * 2048 * 128;
  const int krow0 = tid >> 5, kcol0 = (tid & 31) * 4;
  const char* imgb = img + (size_t)(b * 32) * 32768;

  // ---- prologue: stage tile 0 into buf 0 ----
  if (PRE) {
    *(uint4*)((char*)&Kl[0][0] +    0 + tid * 16) = *(const uint4*)(imgb +     0 + tid * 16);
    *(uint4*)((char*)&Kl[0][0] + 8192 + tid * 16) = *(const uint4*)(imgb +  8192 + tid * 16);
    *(uint4*)((char*)&Vt[0][0] +    0 + tid * 16) = *(const uint4*)(imgb + 16384 + tid * 16);
    *(uint4*)((char*)&Vt[0][0] + 8192 + tid * 16) = *(const uint4*)(imgb + 24576 + tid * 16);
  } else {
#pragma unroll
    for (int i = 0; i < 4; ++i) {
      const int row = krow0 + i * 16;
      float4 x = *(const float4*)(Kp + kvrow0 + row * 128 + kcol0);
      union { s16x4 v; unsigned u[2]; } pk;
      pk.u[0] = cvt_pk_bf16(x.x, x.y);
      pk.u[1] = cvt_pk_bf16(x.z, x.w);
      *(s16x4*)&Kl[0][row * 128 + (kcol0 ^ (8 * (row & 15)))] = pk.v;
    }
    union { float4 v; float f[4]; } r0, r1, r2, r3;
    r0.v = *(const float4*)(Vp + kvrow0 + (kb * 4 + 0) * 128 + db * 4);
    r1.v = *(const float4*)(Vp + kvrow0 + (kb * 4 + 1) * 128 + db * 4);
    r2.v = *(const float4*)(Vp + kvrow0 + (kb * 4 + 2) * 128 + db * 4);
    r3.v = *(const float4*)(Vp + kvrow0 + (kb * 4 + 3) * 128 + db * 4);
    const int cs = (kb * 4) ^ (8 * (db & 7));
#pragma unroll
    for (int j = 0; j < 4; ++j) {
      union { s16x4 v; unsigned u[2]; } pk;
      pk.u[0] = cvt_pk_bf16(r0.f[j], r1.f[j]);
      pk.u[1] = cvt_pk_bf16(r2.f[j], r3.f[j]);
      *(s16x4*)&Vt[0][(db * 4 + j) * 64 + cs] = pk.v;
    }
  }
  __syncthreads();

  // ---- mask words for tile 0 (prefetched one tile ahead thereafter) ----
  unsigned mgc[8];
  if (is8) {
#pragma unroll
    for (int m = 0; m < 4; ++m) {
      mgc[m]     = *(const unsigned*)(mrow8 + hi * 4 + m * 8);
      mgc[4 + m] = *(const unsigned*)(mrow8 + 32 + hi * 4 + m * 8);
    }
  }

  for (int kt = 0; kt < 32; ++kt) {
    const int cur = kt & 1;
    const short* klb = &Kl[cur][0];
    const short* vtb = &Vt[cur][0];
    const int ktn = (kt < 31) ? kt + 1 : 31;

    // ---- issue next-tile staging loads (consumed after PV: full-tile window) ----
    uint4 st0, st1, st2, st3;
    float4 kreg[4], vreg[4];
    if (PRE) {
      const char* s = img + (size_t)(b * 32 + ktn) * 32768;
      st0 = *(const uint4*)(s +     0 + tid * 16);
      st1 = *(const uint4*)(s +  8192 + tid * 16);
      st2 = *(const uint4*)(s + 16384 + tid * 16);
      st3 = *(const uint4*)(s + 24576 + tid * 16);
    } else {
      const size_t nb = kvrow0 + (size_t)ktn * 64 * 128;
#pragma unroll
      for (int i = 0; i < 4; ++i)
        kreg[i] = *(const float4*)(Kp + nb + (krow0 + i * 16) * 128 + kcol0);
#pragma unroll
      for (int i = 0; i < 4; ++i)
        vreg[i] = *(const float4*)(Vp + nb + (kb * 4 + i) * 128 + db * 4);
    }

    // ---- issue next-tile mask words ----
    unsigned mgn[8];
    if (is8) {
#pragma unroll
      for (int m = 0; m < 4; ++m) {
        mgn[m]     = *(const unsigned*)(mrow8 + ktn * 64 + hi * 4 + m * 8);
        mgn[4 + m] = *(const unsigned*)(mrow8 + ktn * 64 + 32 + hi * 4 + m * 8);
      }
    }

    // ---- S^T = K · Q^T (swapped): lane holds S[k][q=l31] ----
    f32x16 s0m, s1m;
#pragma unroll
    for (int r = 0; r < 16; ++r) { s0m[r] = 0.f; s1m[r] = 0.f; }
    __builtin_amdgcn_s_setprio(1);
#pragma unroll
    for (int dc = 0; dc < 8; ++dc) {
      const int colb = (dc * 16 + hi * 8) ^ xk;
      bf16x8 a0 = *(const bf16x8*)&klb[l31 * 128 + colb];
      bf16x8 a1 = *(const bf16x8*)&klb[(32 + l31) * 128 + colb];
      s0m = __builtin_amdgcn_mfma_f32_32x32x16_bf16(a0, qf[dc], s0m, 0, 0, 0);
      s1m = __builtin_amdgcn_mfma_f32_32x32x16_bf16(a1, qf[dc], s1m, 0, 0, 0);
    }
    __builtin_amdgcn_s_setprio(0);

    // ---- mask: reg r <-> k = 32*kk + (r&3) + 8*(r>>2) + 4*hi ----
    float p0[16], p1[16];
    if (is8) {
#pragma unroll
      for (int m = 0; m < 4; ++m)
#pragma unroll
        for (int e = 0; e < 4; ++e) {
          p0[4 * m + e] = ((mgc[m]     >> (8 * e)) & 0xffu) ? MASKV2 : s0m[4 * m + e];
          p1[4 * m + e] = ((mgc[4 + m] >> (8 * e)) & 0xffu) ? MASKV2 : s1m[4 * m + e];
        }
    } else {
#pragma unroll
      for (int m = 0; m < 4; ++m) {
        int4 w0 = *(const int4*)(mrow32 + kt * 64 + hi * 4 + m * 8);
        int4 w1 = *(const int4*)(mrow32 + kt * 64 + 32 + hi * 4 + m * 8);
        p0[4 * m + 0] = w0.x ? MASKV2 : s0m[4 * m + 0];
        p0[4 * m + 1] = w0.y ? MASKV2 : s0m[4 * m + 1];
        p0[4 * m + 2] = w0.z ? MASKV2 : s0m[4 * m + 2];
        p0[4 * m + 3] = w0.w ? MASKV2 : s0m[4 * m + 3];
        p1[4 * m + 0] = w1.x ? MASKV2 : s1m[4 * m + 0];
        p1[4 * m + 1] = w1.y ? MASKV2 : s1m[4 * m + 1];
        p1[4 * m + 2] = w1.z ? MASKV2 : s1m[4 * m + 2];
        p1[4 * m + 3] = w1.w ? MASKV2 : s1m[4 * m + 3];
      }
    }

    // ---- online softmax in exp2 domain ----
    float tm = p0[0];
#pragma unroll
    for (int r = 1; r < 16; ++r) tm = fmaxf(tm, p0[r]);
#pragma unroll
    for (int r = 0; r < 16; ++r) tm = fmaxf(tm, p1[r]);
    tm = fmaxf(tm, __shfl_xor(tm, 32));

    if (__any(tm > mrun + 8.0f)) {        // defer-max (T13)
      float mnew = fmaxf(mrun, tm);
      float corr = __builtin_amdgcn_exp2f(mrun - mnew);
      mrun = mnew;
      lrun *= corr;
#pragma unroll
      for (int g = 0; g < 4; ++g)
#pragma unroll
        for (int r = 0; r < 16; ++r) oacc[g][r] *= corr;
    }

    float psum = 0.f;
#pragma unroll
    for (int r = 0; r < 16; ++r) { p0[r] = __builtin_amdgcn_exp2f(p0[r] - mrun); psum += p0[r]; }
#pragma unroll
    for (int r = 0; r < 16; ++r) { p1[r] = __builtin_amdgcn_exp2f(p1[r] - mrun); psum += p1[r]; }
    psum += __shfl_xor(psum, 32);
    lrun += psum;

    // ---- P (S^T C-layout) -> P^T B-frags, in-register ----
    unsigned pk0[8], pk1[8];
#pragma unroll
    for (int i = 0; i < 8; ++i) {
      pk0[i] = cvt_pk_bf16(p0[2 * i], p0[2 * i + 1]);
      pk1[i] = cvt_pk_bf16(p1[2 * i], p1[2 * i + 1]);
    }
    bf16x8 pa[4];
#pragma unroll
    for (int ks = 0; ks < 4; ++ks) {
      const int base = 4 * (ks & 1);
      unsigned o0, o1, sd0, sd1;
      if (ks < 2) {
        o0  = hi ? pk0[base + 2] : pk0[base + 0];
        o1  = hi ? pk0[base + 3] : pk0[base + 1];
        sd0 = hi ? pk0[base + 0] : pk0[base + 2];
        sd1 = hi ? pk0[base + 1] : pk0[base + 3];
      } else {
        o0  = hi ? pk1[base + 2] : pk1[base + 0];
        o1  = hi ? pk1[base + 3] : pk1[base + 1];
        sd0 = hi ? pk1[base + 0] : pk1[base + 2];
        sd1 = hi ? pk1[base + 1] : pk1[base + 3];
      }
      unsigned rec0 = (unsigned)__shfl_xor((int)sd0, 32);
      unsigned rec1 = (unsigned)__shfl_xor((int)sd1, 32);
      union { bf16x8 v; unsigned u[4]; } uu;
      uu.u[0] = hi ? rec0 : o0;
      uu.u[1] = hi ? rec1 : o1;
      uu.u[2] = hi ? o0 : rec0;
      uu.u[3] = hi ? o1 : rec1;
      pa[ks] = uu.v;
    }

    // ---- O^T += V^T · P^T ----
    __builtin_amdgcn_s_setprio(1);
#pragma unroll
    for (int g = 0; g < 4; ++g) {
      const int drow = g * 32 + l31;
#pragma unroll
      for (int ks = 0; ks < 4; ++ks) {
        bf16x8 va = *(const bf16x8*)&vtb[drow * 64 + ((ks * 16 + hi * 8) ^ xv)];
        oacc[g] = __builtin_amdgcn_mfma_f32_32x32x16_bf16(va, pa[ks], oacc[g], 0, 0, 0);
      }
    }
    __builtin_amdgcn_s_setprio(0);

    // ---- write staged tile -> buf[cur^1] (loads have had the full tile) ----
    if (PRE) {
      char* kd = (char*)&Kl[cur ^ 1][0];
      char* vd = (char*)&Vt[cur ^ 1][0];
      *(uint4*)(kd +    0 + tid * 16) = st0;
      *(uint4*)(kd + 8192 + tid * 16) = st1;
      *(uint4*)(vd +    0 + tid * 16) = st2;
      *(uint4*)(vd + 8192 + tid * 16) = st3;
    } else {
      short* kln = &Kl[cur ^ 1][0];
      short* vtn = &Vt[cur ^ 1][0];
#pragma unroll
      for (int i = 0; i < 4; ++i) {
        const int row = krow0 + i * 16;
        union { s16x4 v; unsigned u[2]; } pk;
        pk.u[0] = cvt_pk_bf16(kreg[i].x, kreg[i].y);
        pk.u[1] = cvt_pk_bf16(kreg[i].z, kreg[i].w);
        *(s16x4*)&kln[row * 128 + (kcol0 ^ (8 * (row & 15)))] = pk.v;
      }
      const int cs = (kb * 4) ^ (8 * (db & 7));
#pragma unroll
      for (int j = 0; j < 4; ++j) {
        union { s16x4 v; unsigned u[2]; } pk;
        union { float4 v; float f[4]; } a0, a1, a2, a3;
        a0.v = vreg[0]; a1.v = vreg[1]; a2.v = vreg[2]; a3.v = vreg[3];
        pk.u[0] = cvt_pk_bf16(a0.f[j], a1.f[j]);
        pk.u[1] = cvt_pk_bf16(a2.f[j], a3.f[j]);
        *(s16x4*)&vtn[(db * 4 + j) * 64 + cs] = pk.v;
      }
    }
    __syncthreads();

    if (is8) {
#pragma unroll
      for (int m = 0; m < 8; ++m) mgc[m] = mgn[m];
    }
  }

  // ---- epilogue: O[q][d] = oacc/l; d = 32g + 4hi + 8m + e ----
  const float inv = 1.0f / lrun;
  float* orow = Op + ((size_t)b * 2048 + q) * 128;
#pragma unroll
  for (int g = 0; g < 4; ++g) {
#pragma unroll
    for (int m = 0; m < 4; ++m) {
      float4 o;
      o.x = oacc[g][4 * m + 0] * inv;
      o.y = oacc[g][4 * m + 1] * inv;
      o.z = oacc[g][4 * m + 2] * inv;
      o.w = oacc[g][4 * m + 3] * inv;
      *(float4*)(orow + g * 32 + hi * 4 + m * 8) = o;
    }
  }
}

extern "C" void kernel_launch(void* const* d_in, const int* in_sizes, int n_in,
                              void* d_out, int out_size, void* d_ws, size_t ws_size,
                              hipStream_t stream) {
  const float* qp = (const float*)d_in[0];
  const float* kp = (const float*)d_in[1];
  const float* vp = (const float*)d_in[2];
  const unsigned char* mp = (const unsigned char*)d_in[3];
  float* op = (float*)d_out;
  int* flag = (int*)d_ws;

  detect_mask_kernel<<<1, 256, 0, stream>>>(mp, flag);

  const size_t need = 256 + (size_t)1024 * 32768;   // 32 MB of tile images
  if (ws_size >= need) {
    char* img = (char*)d_ws + 256;
    build_images<<<1024, 512, 0, stream>>>(kp, vp, img);
    attn_fwd<true><<<256, 512, 0, stream>>>(qp, kp, vp, mp, img, op, flag);
  } else {
    attn_fwd<false><<<256, 512, 0, stream>>>(qp, kp, vp, mp, (const char*)d_ws, op, flag);
  }
}